// Round 1
// baseline (3586.386 us; speedup 1.0000x reference)
//
#include <hip/hip_runtime.h>
#include <hip/hip_fp16.h>

// BiLSTM-CRF forward, MI355X. Round 1: correctness-first full pipeline.
// Pipeline: seqlen -> emb gather(bf16) -> xg GEMM (MFMA bf16, both dirs)
//           -> LSTM recurrence (1 WG per (batch,dir), f16 weights streamed from L2)
//           -> dense logits -> CRF score/forward.

typedef unsigned int  uint32;
typedef unsigned short ushort16;
typedef __attribute__((ext_vector_type(8))) short  short8;   // 8 bf16 (4 VGPRs) — MFMA A/B frag
typedef __attribute__((ext_vector_type(4))) float  floatx4;  // MFMA C/D frag
typedef __attribute__((ext_vector_type(2))) _Float16 half2t;

#define BB 64
#define TT 512
#define NT (BB*TT)        // 32768 rows
#define G4 1024           // 4*H
#define NL 9

__device__ inline float bf2f(ushort16 u) {
  return __builtin_bit_cast(float, ((uint32)u) << 16);
}
__device__ inline ushort16 f2bf(float f) {  // RN-even bf16
  uint32 u = __builtin_bit_cast(uint32, f);
  u += 0x7fffu + ((u >> 16) & 1u);
  return (ushort16)(u >> 16);
}
__device__ inline float sigf(float x)  { return 1.0f / (1.0f + __expf(-x)); }
__device__ inline float tanhf_(float x){ return 1.0f - 2.0f / (1.0f + __expf(2.0f * x)); }

__device__ inline float dot2acc(uint32 w, half2t h, float acc) {
#if __has_builtin(__builtin_amdgcn_fdot2)
  return __builtin_amdgcn_fdot2(__builtin_bit_cast(half2t, w), h, acc, false);
#else
  half2t wv = __builtin_bit_cast(half2t, w);
  return acc + (float)wv[0] * (float)h[0] + (float)wv[1] * (float)h[1];
#endif
}

// ---------------- K1: seq_len ----------------
__global__ __launch_bounds__(64) void k_seqlen(const int* __restrict__ tokens,
                                               int* __restrict__ slen,
                                               float* __restrict__ out_sl) {
  const int b = blockIdx.x, lane = threadIdx.x;
  int cnt = 0;
  for (int t = lane; t < TT; t += 64) cnt += (tokens[b * TT + t] != 0) ? 1 : 0;
  #pragma unroll
  for (int off = 32; off >= 1; off >>= 1) cnt += __shfl_down(cnt, off, 64);
  if (lane == 0) { slen[b] = cnt; out_sl[b] = (float)cnt; }
}

// ---------------- K2a: embedding gather -> bf16 A matrix [NT][256] ----------------
__global__ __launch_bounds__(256) void k_embed(const int* __restrict__ tokens,
                                               const float* __restrict__ emb,
                                               ushort16* __restrict__ A) {
  const int f = blockIdx.x * 256 + threadIdx.x;  // float4 group, NT*256/4 total
  const int e = f * 4;
  const int row = e >> 8;
  const int col = e & 255;
  const int tok = tokens[row];
  const float4 v = *(const float4*)(emb + (size_t)tok * 256 + col);
  uint32 lo = (uint32)f2bf(v.x) | ((uint32)f2bf(v.y) << 16);
  uint32 hi = (uint32)f2bf(v.z) | ((uint32)f2bf(v.w) << 16);
  *(uint2*)(A + e) = make_uint2(lo, hi);
}

// ---------------- K2b: BT[c][k] = Wx_{f|b}[k][c] bf16, c in [0,2048) ----------------
__global__ __launch_bounds__(256) void k_wxprep(const float* __restrict__ Wxf,
                                                const float* __restrict__ Wxb,
                                                ushort16* __restrict__ BT) {
  const int id = blockIdx.x * 256 + threadIdx.x;   // 2048*256
  const int c = id >> 8, k = id & 255;
  const float v = (c < G4) ? Wxf[k * G4 + c] : Wxb[k * G4 + (c - G4)];
  BT[c * 256 + k] = f2bf(v);
}

// ---------------- K2c: Wh -> half2 pack, layout [k2][1024] ----------------
__global__ __launch_bounds__(256) void k_whprep(const float* __restrict__ Wh,
                                                uint32* __restrict__ W2) {
  const int id = blockIdx.x * 256 + threadIdx.x;   // 128*1024
  const int k2 = id >> 10, c = id & 1023;
  const float w0 = Wh[(2 * k2) * G4 + c];
  const float w1 = Wh[(2 * k2 + 1) * G4 + c];
  const ushort16 b0 = __builtin_bit_cast(ushort16, (_Float16)w0);
  const ushort16 b1 = __builtin_bit_cast(ushort16, (_Float16)w1);
  W2[id] = ((uint32)b1 << 16) | (uint32)b0;
}

// ---------------- K3: xg GEMM  [NT,256] @ [256,2048] -> bf16 xg_f | xg_b ----------------
// 64x64 tile, 4 waves, 16x16x32 bf16 MFMA. LDS stride 36 shorts (conflict-free b64 frag reads).
__global__ __launch_bounds__(256) void k_gemm_xg(const ushort16* __restrict__ A,
                                                 const ushort16* __restrict__ BT,
                                                 const float* __restrict__ bias_f,
                                                 const float* __restrict__ bias_b,
                                                 ushort16* __restrict__ xgf,
                                                 ushort16* __restrict__ xgb) {
  __shared__ __align__(16) ushort16 As[64 * 36];
  __shared__ __align__(16) ushort16 Bs[64 * 36];
  const int m0 = blockIdx.x * 64;
  const int n0 = blockIdx.y * 64;
  const int tid = threadIdx.x;
  const int wave = tid >> 6, lane = tid & 63;
  const int lr = tid >> 2;            // staging row 0..63
  const int lc = (tid & 3) * 8;       // staging col {0,8,16,24}
  const int am = lane & 15, aq = lane >> 4;
  floatx4 acc[4];
  #pragma unroll
  for (int j = 0; j < 4; ++j) acc[j] = (floatx4){0.f, 0.f, 0.f, 0.f};

  for (int k0 = 0; k0 < 256; k0 += 32) {
    const uint4 va = *(const uint4*)(A  + ((m0 + lr) * 256 + k0 + lc));
    const uint4 vb = *(const uint4*)(BT + ((n0 + lr) * 256 + k0 + lc));
    *(uint2*)&As[lr * 36 + lc]     = make_uint2(va.x, va.y);
    *(uint2*)&As[lr * 36 + lc + 4] = make_uint2(va.z, va.w);
    *(uint2*)&Bs[lr * 36 + lc]     = make_uint2(vb.x, vb.y);
    *(uint2*)&Bs[lr * 36 + lc + 4] = make_uint2(vb.z, vb.w);
    __syncthreads();
    union { uint2 u[2]; short8 s; } fa, fb;
    fa.u[0] = *(const uint2*)&As[(wave * 16 + am) * 36 + aq * 8];
    fa.u[1] = *(const uint2*)&As[(wave * 16 + am) * 36 + aq * 8 + 4];
    #pragma unroll
    for (int j = 0; j < 4; ++j) {
      fb.u[0] = *(const uint2*)&Bs[(j * 16 + am) * 36 + aq * 8];
      fb.u[1] = *(const uint2*)&Bs[(j * 16 + am) * 36 + aq * 8 + 4];
      acc[j] = __builtin_amdgcn_mfma_f32_16x16x32_bf16(fa.s, fb.s, acc[j], 0, 0, 0);
    }
    __syncthreads();
  }
  // C/D layout (m89/m91-verified): col = lane&15, row = (lane>>4)*4 + reg
  const int orow = m0 + wave * 16 + aq * 4;
  #pragma unroll
  for (int j = 0; j < 4; ++j) {
    const int col = n0 + j * 16 + am;
    const float bv = (col < G4) ? bias_f[col] : bias_b[col - G4];
    #pragma unroll
    for (int r = 0; r < 4; ++r) {
      const float v = acc[j][r] + bv;
      const int row = orow + r;
      if (col < G4) xgf[row * G4 + col] = f2bf(v);
      else          xgb[row * G4 + (col - G4)] = f2bf(v);
    }
  }
}

// ---------------- K4: LSTM recurrence, 1 WG per (batch,dir) ----------------
// thread t owns h-index t: computes gates i,f,g,o at cols {t,256+t,512+t,768+t},
// keeps c[t] in a register across all 512 steps. h broadcast via LDS (f16).
__global__ __launch_bounds__(256) void k_lstm(const ushort16* __restrict__ xgf,
                                              const ushort16* __restrict__ xgb,
                                              const uint32* __restrict__ Whf,
                                              const uint32* __restrict__ Whb,
                                              float* __restrict__ enc) {
  __shared__ __align__(8) _Float16 h_sh[256];
  const int bi = blockIdx.x;
  const int dir = bi >> 6, b = bi & 63;
  const int tid = threadIdx.x;
  const ushort16* xg = dir ? xgb : xgf;
  const uint32* W = (dir ? Whb : Whf) + tid;
  h_sh[tid] = (_Float16)0.f;
  __syncthreads();
  float c = 0.f;
  const half2t* h2 = (const half2t*)h_sh;
  for (int s = 0; s < TT; ++s) {
    const int t = dir ? (TT - 1 - s) : s;
    const int row = b * TT + t;
    const ushort16* xr = xg + row * G4;
    float a0 = bf2f(xr[tid]);
    float a1 = bf2f(xr[256 + tid]);
    float a2 = bf2f(xr[512 + tid]);
    float a3 = bf2f(xr[768 + tid]);
    #pragma unroll 8
    for (int k2 = 0; k2 < 128; ++k2) {
      const half2t hh = h2[k2];                 // wave-uniform address -> LDS broadcast
      const uint32* wr = W + k2 * 1024;
      a0 = dot2acc(wr[0],   hh, a0);
      a1 = dot2acc(wr[256], hh, a1);
      a2 = dot2acc(wr[512], hh, a2);
      a3 = dot2acc(wr[768], hh, a3);
    }
    const float ig = sigf(a0), fg = sigf(a1), gg = tanhf_(a2), og = sigf(a3);
    c = fg * c + ig * gg;
    const float h = og * tanhf_(c);
    __syncthreads();                 // all reads of h_sh(t-1) done
    h_sh[tid] = (_Float16)h;
    enc[row * 512 + dir * 256 + tid] = h;
    __syncthreads();                 // h_sh(t) visible
  }
}

// ---------------- K5: logits = enc @ W_dense + b ----------------
__global__ __launch_bounds__(256) void k_dense(const float* __restrict__ enc,
                                               const float* __restrict__ Wd,
                                               const float* __restrict__ bd,
                                               float* __restrict__ logits) {
  __shared__ float Wl[512 * NL];
  __shared__ float bl[NL];
  const int tid = threadIdx.x;
  for (int i = tid; i < 512 * NL; i += 256) Wl[i] = Wd[i];
  if (tid < NL) bl[tid] = bd[tid];
  __syncthreads();
  const int wave = tid >> 6, lane = tid & 63;
  const int row = blockIdx.x * 4 + wave;
  const float* er = enc + (size_t)row * 512;
  float p[NL];
  #pragma unroll
  for (int c = 0; c < NL; ++c) p[c] = 0.f;
  #pragma unroll
  for (int u = 0; u < 8; ++u) {
    const int k = u * 64 + lane;    // interleaved k: lane-stride 9 floats in LDS -> no conflicts
    const float v = er[k];
    const float* wr = &Wl[k * NL];
    #pragma unroll
    for (int c = 0; c < NL; ++c) p[c] += v * wr[c];
  }
  #pragma unroll
  for (int c = 0; c < NL; ++c) {
    #pragma unroll
    for (int off = 32; off >= 1; off >>= 1) p[c] += __shfl_down(p[c], off, 64);
  }
  if (lane == 0) {
    float* orow = logits + (size_t)row * NL;
    #pragma unroll
    for (int c = 0; c < NL; ++c) orow[c] = p[c] + bl[c];
  }
}

// ---------------- K6: CRF log-likelihood ----------------
__global__ __launch_bounds__(64) void k_crf(const float* __restrict__ logits,
                                            const int* __restrict__ labels,
                                            const int* __restrict__ slen,
                                            const float* __restrict__ trans,
                                            float* __restrict__ out_ll) {
  __shared__ float tr[NL * NL];
  __shared__ float alpha[NL];
  const int b = blockIdx.x;
  const int lane = threadIdx.x;
  for (int i = lane; i < NL * NL; i += 64) tr[i] = trans[i];
  __syncthreads();
  const int len = slen[b];
  const int* tg = labels + b * TT;
  const float* lg = logits + (size_t)b * TT * NL;
  // gold score
  float s = 0.f;
  for (int t = lane; t < TT; t += 64)
    if (t < len) s += lg[t * NL + tg[t]];
  for (int t = lane; t < TT - 1; t += 64)
    if (t + 1 < len) s += tr[tg[t] * NL + tg[t + 1]];
  #pragma unroll
  for (int off = 32; off >= 1; off >>= 1) s += __shfl_down(s, off, 64);
  // forward algorithm (lanes 0..8, single wave -> lockstep, no barriers needed)
  if (lane < NL) alpha[lane] = lg[lane];
  __syncthreads();
  if (lane < NL) {
    const int j = lane;
    for (int t = 1; t < TT; ++t) {
      if (t < len) {
        float av[NL];
        float m = -1e30f;
        #pragma unroll
        for (int i = 0; i < NL; ++i) { av[i] = alpha[i] + tr[i * NL + j]; m = fmaxf(m, av[i]); }
        float ss = 0.f;
        #pragma unroll
        for (int i = 0; i < NL; ++i) ss += __expf(av[i] - m);
        const float nj = m + __logf(ss) + lg[t * NL + j];
        alpha[j] = nj;   // lockstep: all lanes' reads above retire before this store
      }
    }
  }
  __syncthreads();
  if (lane == 0) {
    float m = -1e30f;
    #pragma unroll
    for (int i = 0; i < NL; ++i) m = fmaxf(m, alpha[i]);
    float ss = 0.f;
    #pragma unroll
    for (int i = 0; i < NL; ++i) ss += __expf(alpha[i] - m);
    out_ll[b] = s - (m + __logf(ss));
  }
}

extern "C" void kernel_launch(void* const* d_in, const int* in_sizes, int n_in,
                              void* d_out, int out_size, void* d_ws, size_t ws_size,
                              hipStream_t stream) {
  (void)in_sizes; (void)n_in; (void)out_size; (void)ws_size;
  const int*   tokens = (const int*)d_in[0];
  const int*   labels = (const int*)d_in[1];
  const float* emb    = (const float*)d_in[2];
  const float* Wxf    = (const float*)d_in[3];
  const float* Whf    = (const float*)d_in[4];
  const float* bf_    = (const float*)d_in[5];
  const float* Wxb    = (const float*)d_in[6];
  const float* Whb    = (const float*)d_in[7];
  const float* bb_    = (const float*)d_in[8];
  const float* Wd     = (const float*)d_in[9];
  const float* bd     = (const float*)d_in[10];
  const float* trans  = (const float*)d_in[11];
  float* out = (float*)d_out;   // [logits 294912][seq_len 64][ll 64]

  char* ws = (char*)d_ws;       // ~210 MB total
  ushort16* A    = (ushort16*)(ws + 0);           // 16 MB  bf16 emb rows
  ushort16* BT   = (ushort16*)(ws + 16777216);    //  1 MB  Wx^T bf16 (2048x256)
  uint32*   W2f  = (uint32*)  (ws + 17825792);    // 512 KB Wh_f half2 [128][1024]
  uint32*   W2b  = (uint32*)  (ws + 18350080);    // 512 KB
  ushort16* xgf  = (ushort16*)(ws + 18874368);    // 64 MB  bf16 [NT][1024]
  ushort16* xgb  = (ushort16*)(ws + 85983232);    // 64 MB
  float*    enc  = (float*)   (ws + 153092096);   // 64 MB  fp32 [NT][512]
  int*      slen = (int*)     (ws + 220200960);   // 256 B

  k_seqlen<<<BB, 64, 0, stream>>>(tokens, slen, out + NT * NL);
  k_embed <<<NT * 256 / 4 / 256, 256, 0, stream>>>(tokens, emb, A);
  k_wxprep<<<2048 * 256 / 256, 256, 0, stream>>>(Wxf, Wxb, BT);
  k_whprep<<<128 * 1024 / 256, 256, 0, stream>>>(Whf, W2f);
  k_whprep<<<128 * 1024 / 256, 256, 0, stream>>>(Whb, W2b);
  k_gemm_xg<<<dim3(NT / 64, 2048 / 64), 256, 0, stream>>>(A, BT, bf_, bb_, xgf, xgb);
  k_lstm  <<<128, 256, 0, stream>>>(xgf, xgb, W2f, W2b, enc);
  k_dense <<<NT / 4, 256, 0, stream>>>(enc, Wd, bd, out);
  k_crf   <<<BB, 64, 0, stream>>>(out, labels, slen, trans, out + NT * NL + BB);
}

// Round 2
// 1486.688 us; speedup vs baseline: 2.4123x; 2.4123x over previous
//
#include <hip/hip_runtime.h>
#include <hip/hip_fp16.h>

// BiLSTM-CRF forward, MI355X. Round 2: CU-resident LSTM weights.
// k_lstm v2: Wh(f16) split 384KB regs + 128KB LDS per CU; h broadcast via
// v_readlane->SGPR->v_dot2; no per-step weight streaming from L2.

typedef unsigned int  uint32;
typedef unsigned short ushort16;
typedef __attribute__((ext_vector_type(8))) short  short8;   // 8 bf16 (4 VGPRs) — MFMA A/B frag
typedef __attribute__((ext_vector_type(4))) float  floatx4;  // MFMA C/D frag
typedef __attribute__((ext_vector_type(2))) _Float16 half2t;

#define BB 64
#define TT 512
#define NT (BB*TT)        // 32768 rows
#define G4 1024           // 4*H
#define NL 9
#define KR 96             // k2 rows register-resident (of 128)
#define KL 32             // k2 rows LDS-resident

__device__ inline float bf2f(ushort16 u) {
  return __builtin_bit_cast(float, ((uint32)u) << 16);
}
__device__ inline ushort16 f2bf(float f) {  // RN-even bf16
  uint32 u = __builtin_bit_cast(uint32, f);
  u += 0x7fffu + ((u >> 16) & 1u);
  return (ushort16)(u >> 16);
}
__device__ inline float sigf(float x)  { return 1.0f / (1.0f + __expf(-x)); }
__device__ inline float tanhf_(float x){ return 1.0f - 2.0f / (1.0f + __expf(2.0f * x)); }

__device__ inline float fdot2_(uint32 w, half2t h, float acc) {
  return __builtin_amdgcn_fdot2(__builtin_bit_cast(half2t, w), h, acc, false);
}

// ---------------- K1: seq_len ----------------
__global__ __launch_bounds__(64) void k_seqlen(const int* __restrict__ tokens,
                                               int* __restrict__ slen,
                                               float* __restrict__ out_sl) {
  const int b = blockIdx.x, lane = threadIdx.x;
  int cnt = 0;
  for (int t = lane; t < TT; t += 64) cnt += (tokens[b * TT + t] != 0) ? 1 : 0;
  #pragma unroll
  for (int off = 32; off >= 1; off >>= 1) cnt += __shfl_down(cnt, off, 64);
  if (lane == 0) { slen[b] = cnt; out_sl[b] = (float)cnt; }
}

// ---------------- K2a: embedding gather -> bf16 A matrix [NT][256] ----------------
__global__ __launch_bounds__(256) void k_embed(const int* __restrict__ tokens,
                                               const float* __restrict__ emb,
                                               ushort16* __restrict__ A) {
  const int f = blockIdx.x * 256 + threadIdx.x;  // float4 group, NT*256/4 total
  const int e = f * 4;
  const int row = e >> 8;
  const int col = e & 255;
  const int tok = tokens[row];
  const float4 v = *(const float4*)(emb + (size_t)tok * 256 + col);
  uint32 lo = (uint32)f2bf(v.x) | ((uint32)f2bf(v.y) << 16);
  uint32 hi = (uint32)f2bf(v.z) | ((uint32)f2bf(v.w) << 16);
  *(uint2*)(A + e) = make_uint2(lo, hi);
}

// ---------------- K2b: BT[c][k] = Wx_{f|b}[k][c] bf16, c in [0,2048) ----------------
__global__ __launch_bounds__(256) void k_wxprep(const float* __restrict__ Wxf,
                                                const float* __restrict__ Wxb,
                                                ushort16* __restrict__ BT) {
  const int id = blockIdx.x * 256 + threadIdx.x;   // 2048*256
  const int c = id >> 8, k = id & 255;
  const float v = (c < G4) ? Wxf[k * G4 + c] : Wxb[k * G4 + (c - G4)];
  BT[c * 256 + k] = f2bf(v);
}

// ---------------- K2c: Wh -> half2 pack, layout [k2][1024] ----------------
__global__ __launch_bounds__(256) void k_whprep(const float* __restrict__ Wh,
                                                uint32* __restrict__ W2) {
  const int id = blockIdx.x * 256 + threadIdx.x;   // 128*1024
  const int k2 = id >> 10, c = id & 1023;
  const float w0 = Wh[(2 * k2) * G4 + c];
  const float w1 = Wh[(2 * k2 + 1) * G4 + c];
  const ushort16 b0 = __builtin_bit_cast(ushort16, (_Float16)w0);
  const ushort16 b1 = __builtin_bit_cast(ushort16, (_Float16)w1);
  W2[id] = ((uint32)b1 << 16) | (uint32)b0;
}

// ---------------- K3: xg GEMM  [NT,256] @ [256,2048] -> bf16 xg_f | xg_b ----------------
__global__ __launch_bounds__(256) void k_gemm_xg(const ushort16* __restrict__ A,
                                                 const ushort16* __restrict__ BT,
                                                 const float* __restrict__ bias_f,
                                                 const float* __restrict__ bias_b,
                                                 ushort16* __restrict__ xgf,
                                                 ushort16* __restrict__ xgb) {
  __shared__ __align__(16) ushort16 As[64 * 36];
  __shared__ __align__(16) ushort16 Bs[64 * 36];
  const int m0 = blockIdx.x * 64;
  const int n0 = blockIdx.y * 64;
  const int tid = threadIdx.x;
  const int wave = tid >> 6, lane = tid & 63;
  const int lr = tid >> 2;            // staging row 0..63
  const int lc = (tid & 3) * 8;       // staging col {0,8,16,24}
  const int am = lane & 15, aq = lane >> 4;
  floatx4 acc[4];
  #pragma unroll
  for (int j = 0; j < 4; ++j) acc[j] = (floatx4){0.f, 0.f, 0.f, 0.f};

  for (int k0 = 0; k0 < 256; k0 += 32) {
    const uint4 va = *(const uint4*)(A  + ((m0 + lr) * 256 + k0 + lc));
    const uint4 vb = *(const uint4*)(BT + ((n0 + lr) * 256 + k0 + lc));
    *(uint2*)&As[lr * 36 + lc]     = make_uint2(va.x, va.y);
    *(uint2*)&As[lr * 36 + lc + 4] = make_uint2(va.z, va.w);
    *(uint2*)&Bs[lr * 36 + lc]     = make_uint2(vb.x, vb.y);
    *(uint2*)&Bs[lr * 36 + lc + 4] = make_uint2(vb.z, vb.w);
    __syncthreads();
    union { uint2 u[2]; short8 s; } fa, fb;
    fa.u[0] = *(const uint2*)&As[(wave * 16 + am) * 36 + aq * 8];
    fa.u[1] = *(const uint2*)&As[(wave * 16 + am) * 36 + aq * 8 + 4];
    #pragma unroll
    for (int j = 0; j < 4; ++j) {
      fb.u[0] = *(const uint2*)&Bs[(j * 16 + am) * 36 + aq * 8];
      fb.u[1] = *(const uint2*)&Bs[(j * 16 + am) * 36 + aq * 8 + 4];
      acc[j] = __builtin_amdgcn_mfma_f32_16x16x32_bf16(fa.s, fb.s, acc[j], 0, 0, 0);
    }
    __syncthreads();
  }
  // C/D layout (m89/m91-verified): col = lane&15, row = (lane>>4)*4 + reg
  const int orow = m0 + wave * 16 + aq * 4;
  #pragma unroll
  for (int j = 0; j < 4; ++j) {
    const int col = n0 + j * 16 + am;
    const float bv = (col < G4) ? bias_f[col] : bias_b[col - G4];
    #pragma unroll
    for (int r = 0; r < 4; ++r) {
      const float v = acc[j][r] + bv;
      const int row = orow + r;
      if (col < G4) xgf[row * G4 + col] = f2bf(v);
      else          xgb[row * G4 + (col - G4)] = f2bf(v);
    }
  }
}

// ---------------- K4: LSTM recurrence v2 — CU-resident weights ----------------
// 1 WG per (dir,batch); 512 threads (8 waves, 2 waves/SIMD, <=256 VGPR).
// Wave w owns gate-cols [128w,128w+128); lane owns cols colA=128w+l, colB=colA+64.
// Wh(half2 along k): rows k2 in [0,96) in VGPRs; rows [96,128) in LDS (128 KB).
// h broadcast: 4x ds_read_b32 of packed h, then v_readlane -> SGPR operand of
// v_dot2_f32_f16 (1 SGPR src legal in VOP3P). No reduction: lane owns full col.
__global__ __launch_bounds__(512, 2) void k_lstm(const ushort16* __restrict__ xgf,
                                                 const ushort16* __restrict__ xgb,
                                                 const uint32* __restrict__ Whf,
                                                 const uint32* __restrict__ Whb,
                                                 float* __restrict__ enc) {
  __shared__ uint32 WL[KL * 1024];        // 128 KB, pair-interleaved per wave
  __shared__ float gate[1024];            // 4 KB
  __shared__ ushort16 h16[2][256];        // 1 KB, f16 h double-buffered
  const int bi = blockIdx.x;
  const int dir = bi >> 6, b = bi & 63;
  const int tid = threadIdx.x;
  const int w = tid >> 6, l = tid & 63;
  const int colA = w * 128 + l;
  const int colB = colA + 64;
  const ushort16* xg = dir ? xgb : xgf;
  const uint32* W2 = dir ? Whb : Whf;

  // Stage LDS-resident rows, interleaved so lane reads (colA,colB) as one b64:
  // dword index = k2r*1024 + (c>>7)*128 + (c&63)*2 + ((c>>6)&1)
  for (int idx = tid; idx < KL * 1024; idx += 512) {
    const int k2r = idx >> 10, c = idx & 1023;
    WL[k2r * 1024 + ((c >> 7) << 7) + ((c & 63) << 1) + ((c >> 6) & 1)] =
        W2[(KR + k2r) * 1024 + c];
  }
  // Register-resident rows (loaded once; full unroll keeps them in VGPRs)
  uint32 wA[KR], wB[KR];
  #pragma unroll
  for (int i = 0; i < KR; ++i) {
    wA[i] = W2[i * 1024 + colA];
    wB[i] = W2[i * 1024 + colB];
  }
  if (tid < 128) ((uint32*)h16[0])[tid] = 0u;
  float c_state = 0.f;                    // live in lanes tid<256
  __syncthreads();

  for (int s = 0; s < TT; ++s) {
    const int t = dir ? (TT - 1 - s) : s;
    const int row = b * TT + t;
    const ushort16* xr = xg + (size_t)row * G4;
    // xg already contains bias (folded in GEMM epilogue)
    float acc0 = bf2f(xr[colA]);
    float acc1 = 0.f;
    float acc2 = bf2f(xr[colB]);
    float acc3 = 0.f;
    const uint32* hrd = (const uint32*)h16[s & 1];
    const int hl = l & 31;
    const uint32 hv0 = hrd[hl];
    const uint32 hv1 = hrd[32 + hl];
    const uint32 hv2 = hrd[64 + hl];
    const uint32 hv3 = hrd[96 + hl];
    // chunks 0..2: register weights
    #pragma unroll
    for (int q = 0; q < 3; ++q) {
      const uint32 hvq = (q == 0) ? hv0 : (q == 1) ? hv1 : hv2;
      #pragma unroll
      for (int i = 0; i < 32; ++i) {
        const half2t hh = __builtin_bit_cast(
            half2t, (uint32)__builtin_amdgcn_readlane((int)hvq, i));
        const int k = q * 32 + i;
        if (i & 1) { acc1 = fdot2_(wA[k], hh, acc1); acc3 = fdot2_(wB[k], hh, acc3); }
        else       { acc0 = fdot2_(wA[k], hh, acc0); acc2 = fdot2_(wB[k], hh, acc2); }
      }
    }
    // chunk 3: LDS weights (b64 per k2: [wA|wB] pair; lane stride 2 dwords -> 2-way free)
    {
      const uint32* wl = WL + w * 128 + (l << 1);
      #pragma unroll
      for (int i = 0; i < 32; ++i) {
        const half2t hh = __builtin_bit_cast(
            half2t, (uint32)__builtin_amdgcn_readlane((int)hv3, i));
        const uint2 wp = *(const uint2*)(wl + i * 1024);
        if (i & 1) { acc1 = fdot2_(wp.x, hh, acc1); acc3 = fdot2_(wp.y, hh, acc3); }
        else       { acc0 = fdot2_(wp.x, hh, acc0); acc2 = fdot2_(wp.y, hh, acc2); }
      }
    }
    gate[colA] = acc0 + acc1;
    gate[colB] = acc2 + acc3;
    __syncthreads();
    if (tid < 256) {
      const float gi = gate[tid];
      const float gf = gate[256 + tid];
      const float gg = gate[512 + tid];
      const float go = gate[768 + tid];
      c_state = sigf(gf) * c_state + sigf(gi) * tanhf_(gg);
      const float h = sigf(go) * tanhf_(c_state);
      h16[(s + 1) & 1][tid] = __builtin_bit_cast(ushort16, (_Float16)h);
      enc[(size_t)row * 512 + dir * 256 + tid] = h;
    }
    __syncthreads();
  }
}

// ---------------- K5: logits = enc @ W_dense + b ----------------
__global__ __launch_bounds__(256) void k_dense(const float* __restrict__ enc,
                                               const float* __restrict__ Wd,
                                               const float* __restrict__ bd,
                                               float* __restrict__ logits) {
  __shared__ float Wl[512 * NL];
  __shared__ float bl[NL];
  const int tid = threadIdx.x;
  for (int i = tid; i < 512 * NL; i += 256) Wl[i] = Wd[i];
  if (tid < NL) bl[tid] = bd[tid];
  __syncthreads();
  const int wave = tid >> 6, lane = tid & 63;
  const int row = blockIdx.x * 4 + wave;
  const float* er = enc + (size_t)row * 512;
  float p[NL];
  #pragma unroll
  for (int c = 0; c < NL; ++c) p[c] = 0.f;
  #pragma unroll
  for (int u = 0; u < 8; ++u) {
    const int k = u * 64 + lane;
    const float v = er[k];
    const float* wr = &Wl[k * NL];
    #pragma unroll
    for (int c = 0; c < NL; ++c) p[c] += v * wr[c];
  }
  #pragma unroll
  for (int c = 0; c < NL; ++c) {
    #pragma unroll
    for (int off = 32; off >= 1; off >>= 1) p[c] += __shfl_down(p[c], off, 64);
  }
  if (lane == 0) {
    float* orow = logits + (size_t)row * NL;
    #pragma unroll
    for (int c = 0; c < NL; ++c) orow[c] = p[c] + bl[c];
  }
}

// ---------------- K6: CRF log-likelihood ----------------
__global__ __launch_bounds__(64) void k_crf(const float* __restrict__ logits,
                                            const int* __restrict__ labels,
                                            const int* __restrict__ slen,
                                            const float* __restrict__ trans,
                                            float* __restrict__ out_ll) {
  __shared__ float tr[NL * NL];
  __shared__ float alpha[NL];
  const int b = blockIdx.x;
  const int lane = threadIdx.x;
  for (int i = lane; i < NL * NL; i += 64) tr[i] = trans[i];
  __syncthreads();
  const int len = slen[b];
  const int* tg = labels + b * TT;
  const float* lg = logits + (size_t)b * TT * NL;
  float s = 0.f;
  for (int t = lane; t < TT; t += 64)
    if (t < len) s += lg[t * NL + tg[t]];
  for (int t = lane; t < TT - 1; t += 64)
    if (t + 1 < len) s += tr[tg[t] * NL + tg[t + 1]];
  #pragma unroll
  for (int off = 32; off >= 1; off >>= 1) s += __shfl_down(s, off, 64);
  if (lane < NL) alpha[lane] = lg[lane];
  __syncthreads();
  if (lane < NL) {
    const int j = lane;
    for (int t = 1; t < TT; ++t) {
      if (t < len) {
        float av[NL];
        float m = -1e30f;
        #pragma unroll
        for (int i = 0; i < NL; ++i) { av[i] = alpha[i] + tr[i * NL + j]; m = fmaxf(m, av[i]); }
        float ss = 0.f;
        #pragma unroll
        for (int i = 0; i < NL; ++i) ss += __expf(av[i] - m);
        const float nj = m + __logf(ss) + lg[t * NL + j];
        alpha[j] = nj;
      }
    }
  }
  __syncthreads();
  if (lane == 0) {
    float m = -1e30f;
    #pragma unroll
    for (int i = 0; i < NL; ++i) m = fmaxf(m, alpha[i]);
    float ss = 0.f;
    #pragma unroll
    for (int i = 0; i < NL; ++i) ss += __expf(alpha[i] - m);
    out_ll[b] = s - (m + __logf(ss));
  }
}

extern "C" void kernel_launch(void* const* d_in, const int* in_sizes, int n_in,
                              void* d_out, int out_size, void* d_ws, size_t ws_size,
                              hipStream_t stream) {
  (void)in_sizes; (void)n_in; (void)out_size; (void)ws_size;
  const int*   tokens = (const int*)d_in[0];
  const int*   labels = (const int*)d_in[1];
  const float* emb    = (const float*)d_in[2];
  const float* Wxf    = (const float*)d_in[3];
  const float* Whf    = (const float*)d_in[4];
  const float* bf_    = (const float*)d_in[5];
  const float* Wxb    = (const float*)d_in[6];
  const float* Whb    = (const float*)d_in[7];
  const float* bb_    = (const float*)d_in[8];
  const float* Wd     = (const float*)d_in[9];
  const float* bd     = (const float*)d_in[10];
  const float* trans  = (const float*)d_in[11];
  float* out = (float*)d_out;   // [logits 294912][seq_len 64][ll 64]

  char* ws = (char*)d_ws;
  ushort16* A    = (ushort16*)(ws + 0);           // 16 MB  bf16 emb rows
  ushort16* BT   = (ushort16*)(ws + 16777216);    //  1 MB  Wx^T bf16 (2048x256)
  uint32*   W2f  = (uint32*)  (ws + 17825792);    // 512 KB Wh_f half2 [128][1024]
  uint32*   W2b  = (uint32*)  (ws + 18350080);    // 512 KB
  ushort16* xgf  = (ushort16*)(ws + 18874368);    // 64 MB  bf16 [NT][1024]
  ushort16* xgb  = (ushort16*)(ws + 85983232);    // 64 MB
  float*    enc  = (float*)   (ws + 153092096);   // 64 MB  fp32 [NT][512]
  int*      slen = (int*)     (ws + 220200960);   // 256 B

  k_seqlen<<<BB, 64, 0, stream>>>(tokens, slen, out + NT * NL);
  k_embed <<<NT * 256 / 4 / 256, 256, 0, stream>>>(tokens, emb, A);
  k_wxprep<<<2048 * 256 / 256, 256, 0, stream>>>(Wxf, Wxb, BT);
  k_whprep<<<128 * 1024 / 256, 256, 0, stream>>>(Whf, W2f);
  k_whprep<<<128 * 1024 / 256, 256, 0, stream>>>(Whb, W2b);
  k_gemm_xg<<<dim3(NT / 64, 2048 / 64), 256, 0, stream>>>(A, BT, bf_, bb_, xgf, xgb);
  k_lstm  <<<128, 512, 0, stream>>>(xgf, xgb, W2f, W2b, enc);
  k_dense <<<NT / 4, 256, 0, stream>>>(enc, Wd, bd, out);
  k_crf   <<<BB, 64, 0, stream>>>(out, labels, slen, trans, out + NT * NL + BB);
}

// Round 3
// 1402.588 us; speedup vs baseline: 2.5570x; 1.0600x over previous
//
#include <hip/hip_runtime.h>
#include <hip/hip_fp16.h>

// BiLSTM-CRF forward, MI355X. Round 3: k_lstm v3.
// - Weights pinned in VGPRs via opaque asm (round 2's allocator sank them -> L2 restream).
// - h broadcast via wave-uniform ds_read_b128 (LDS pipe) instead of v_readlane (VALU pipe).
// - x-gate prefetch; conflict-free h16 pack (shfl_xor + even-lane dword writes).

typedef unsigned int  uint32;
typedef unsigned short ushort16;
typedef __attribute__((ext_vector_type(8))) short  short8;   // 8 bf16 (4 VGPRs) — MFMA A/B frag
typedef __attribute__((ext_vector_type(4))) float  floatx4;  // MFMA C/D frag
typedef __attribute__((ext_vector_type(2))) _Float16 half2t;

#define BB 64
#define TT 512
#define NT (BB*TT)        // 32768 rows
#define G4 1024           // 4*H
#define NL 9
#define KR 92             // k2 rows register-resident (92*2 = 184 pinned VGPRs)
#define KL 36             // k2 rows LDS-resident (36*4KB = 147KB)

__device__ inline float bf2f(ushort16 u) {
  return __builtin_bit_cast(float, ((uint32)u) << 16);
}
__device__ inline ushort16 f2bf(float f) {  // RN-even bf16
  uint32 u = __builtin_bit_cast(uint32, f);
  u += 0x7fffu + ((u >> 16) & 1u);
  return (ushort16)(u >> 16);
}
__device__ inline float sigf(float x)  { return 1.0f / (1.0f + __expf(-x)); }
__device__ inline float tanhf_(float x){ return 1.0f - 2.0f / (1.0f + __expf(2.0f * x)); }

__device__ inline float fdot2_(uint32 w, half2t h, float acc) {
  return __builtin_amdgcn_fdot2(__builtin_bit_cast(half2t, w), h, acc, false);
}

// ---------------- K1: seq_len ----------------
__global__ __launch_bounds__(64) void k_seqlen(const int* __restrict__ tokens,
                                               int* __restrict__ slen,
                                               float* __restrict__ out_sl) {
  const int b = blockIdx.x, lane = threadIdx.x;
  int cnt = 0;
  for (int t = lane; t < TT; t += 64) cnt += (tokens[b * TT + t] != 0) ? 1 : 0;
  #pragma unroll
  for (int off = 32; off >= 1; off >>= 1) cnt += __shfl_down(cnt, off, 64);
  if (lane == 0) { slen[b] = cnt; out_sl[b] = (float)cnt; }
}

// ---------------- K2a: embedding gather -> bf16 A matrix [NT][256] ----------------
__global__ __launch_bounds__(256) void k_embed(const int* __restrict__ tokens,
                                               const float* __restrict__ emb,
                                               ushort16* __restrict__ A) {
  const int f = blockIdx.x * 256 + threadIdx.x;  // float4 group, NT*256/4 total
  const int e = f * 4;
  const int row = e >> 8;
  const int col = e & 255;
  const int tok = tokens[row];
  const float4 v = *(const float4*)(emb + (size_t)tok * 256 + col);
  uint32 lo = (uint32)f2bf(v.x) | ((uint32)f2bf(v.y) << 16);
  uint32 hi = (uint32)f2bf(v.z) | ((uint32)f2bf(v.w) << 16);
  *(uint2*)(A + e) = make_uint2(lo, hi);
}

// ---------------- K2b: BT[c][k] = Wx_{f|b}[k][c] bf16, c in [0,2048) ----------------
__global__ __launch_bounds__(256) void k_wxprep(const float* __restrict__ Wxf,
                                                const float* __restrict__ Wxb,
                                                ushort16* __restrict__ BT) {
  const int id = blockIdx.x * 256 + threadIdx.x;   // 2048*256
  const int c = id >> 8, k = id & 255;
  const float v = (c < G4) ? Wxf[k * G4 + c] : Wxb[k * G4 + (c - G4)];
  BT[c * 256 + k] = f2bf(v);
}

// ---------------- K2c: Wh -> half2 pack, layout [k2][1024] ----------------
__global__ __launch_bounds__(256) void k_whprep(const float* __restrict__ Wh,
                                                uint32* __restrict__ W2) {
  const int id = blockIdx.x * 256 + threadIdx.x;   // 128*1024
  const int k2 = id >> 10, c = id & 1023;
  const float w0 = Wh[(2 * k2) * G4 + c];
  const float w1 = Wh[(2 * k2 + 1) * G4 + c];
  const ushort16 b0 = __builtin_bit_cast(ushort16, (_Float16)w0);
  const ushort16 b1 = __builtin_bit_cast(ushort16, (_Float16)w1);
  W2[id] = ((uint32)b1 << 16) | (uint32)b0;
}

// ---------------- K3: xg GEMM  [NT,256] @ [256,2048] -> bf16 xg_f | xg_b ----------------
__global__ __launch_bounds__(256) void k_gemm_xg(const ushort16* __restrict__ A,
                                                 const ushort16* __restrict__ BT,
                                                 const float* __restrict__ bias_f,
                                                 const float* __restrict__ bias_b,
                                                 ushort16* __restrict__ xgf,
                                                 ushort16* __restrict__ xgb) {
  __shared__ __align__(16) ushort16 As[64 * 36];
  __shared__ __align__(16) ushort16 Bs[64 * 36];
  const int m0 = blockIdx.x * 64;
  const int n0 = blockIdx.y * 64;
  const int tid = threadIdx.x;
  const int wave = tid >> 6, lane = tid & 63;
  const int lr = tid >> 2;            // staging row 0..63
  const int lc = (tid & 3) * 8;       // staging col {0,8,16,24}
  const int am = lane & 15, aq = lane >> 4;
  floatx4 acc[4];
  #pragma unroll
  for (int j = 0; j < 4; ++j) acc[j] = (floatx4){0.f, 0.f, 0.f, 0.f};

  for (int k0 = 0; k0 < 256; k0 += 32) {
    const uint4 va = *(const uint4*)(A  + ((m0 + lr) * 256 + k0 + lc));
    const uint4 vb = *(const uint4*)(BT + ((n0 + lr) * 256 + k0 + lc));
    *(uint2*)&As[lr * 36 + lc]     = make_uint2(va.x, va.y);
    *(uint2*)&As[lr * 36 + lc + 4] = make_uint2(va.z, va.w);
    *(uint2*)&Bs[lr * 36 + lc]     = make_uint2(vb.x, vb.y);
    *(uint2*)&Bs[lr * 36 + lc + 4] = make_uint2(vb.z, vb.w);
    __syncthreads();
    union { uint2 u[2]; short8 s; } fa, fb;
    fa.u[0] = *(const uint2*)&As[(wave * 16 + am) * 36 + aq * 8];
    fa.u[1] = *(const uint2*)&As[(wave * 16 + am) * 36 + aq * 8 + 4];
    #pragma unroll
    for (int j = 0; j < 4; ++j) {
      fb.u[0] = *(const uint2*)&Bs[(j * 16 + am) * 36 + aq * 8];
      fb.u[1] = *(const uint2*)&Bs[(j * 16 + am) * 36 + aq * 8 + 4];
      acc[j] = __builtin_amdgcn_mfma_f32_16x16x32_bf16(fa.s, fb.s, acc[j], 0, 0, 0);
    }
    __syncthreads();
  }
  // C/D layout (m89/m91-verified): col = lane&15, row = (lane>>4)*4 + reg
  const int orow = m0 + wave * 16 + aq * 4;
  #pragma unroll
  for (int j = 0; j < 4; ++j) {
    const int col = n0 + j * 16 + am;
    const float bv = (col < G4) ? bias_f[col] : bias_b[col - G4];
    #pragma unroll
    for (int r = 0; r < 4; ++r) {
      const float v = acc[j][r] + bv;
      const int row = orow + r;
      if (col < G4) xgf[row * G4 + col] = f2bf(v);
      else          xgb[row * G4 + (col - G4)] = f2bf(v);
    }
  }
}

// ---------------- K4: LSTM recurrence v3 ----------------
// 1 WG per (dir,batch); 512 threads (8 waves, 2/SIMD, <=256 VGPR).
// Lane owns cols colA=w*128+l, colB=colA+64 (full columns, no reduction).
// Wh rows k2<KR pinned in VGPRs (asm barrier -> not rematerializable);
// rows [KR,128) in LDS laid out per-wave: idx = w*KL*128 + k2r*128 + 2*l + pair.
// h broadcast: wave-uniform ds_read_b128 of packed-f16 h (LDS pipe, overlaps VALU).
__global__ __launch_bounds__(512, 2) void k_lstm(const ushort16* __restrict__ xgf,
                                                 const ushort16* __restrict__ xgb,
                                                 const uint32* __restrict__ Whf,
                                                 const uint32* __restrict__ Whb,
                                                 float* __restrict__ enc) {
  __shared__ uint32 WL[KL * 1024];               // 147456 B
  __shared__ float gate[1024];                   // 4 KB
  __shared__ __align__(16) uint32 h2buf[2][128]; // packed f16 h, double-buffered
  const int bi = blockIdx.x;
  const int dir = bi >> 6, b = bi & 63;
  const int tid = threadIdx.x;
  const int w = tid >> 6, l = tid & 63;
  const int colA = w * 128 + l;
  const int colB = colA + 64;
  const ushort16* xg = dir ? xgb : xgf;
  const uint32* W2 = dir ? Whb : Whf;

  // Stage LDS-resident k2 rows. For col c: wave w=c>>7, pair=(c>>6)&1, l=c&63.
  for (int idx = tid; idx < KL * 1024; idx += 512) {
    const int k2r = idx >> 10, c = idx & 1023;
    WL[(c >> 7) * (KL * 128) + k2r * 128 + ((c & 63) << 1) + ((c >> 6) & 1)] =
        W2[(KR + k2r) * 1024 + c];
  }
  // Register-resident rows: load once, then pin with an opaque asm barrier so
  // the allocator cannot sink/rematerialize the loads into the step loop.
  uint32 wA[KR], wB[KR];
  #pragma unroll
  for (int i = 0; i < KR; ++i) {
    wA[i] = W2[i * 1024 + colA];
    wB[i] = W2[i * 1024 + colB];
  }
  #pragma unroll
  for (int i = 0; i < KR; ++i) asm volatile("" : "+v"(wA[i]), "+v"(wB[i]));

  if (tid < 128) h2buf[0][tid] = 0u;
  float c_state = 0.f;                    // live in lanes tid<256
  __syncthreads();

  const uint32* wl = WL + w * (KL * 128) + (l << 1);
  // x prefetch for step 0
  {
  }
  const int t0 = dir ? (TT - 1) : 0;
  ushort16 xA = xg[(size_t)(b * TT + t0) * G4 + colA];
  ushort16 xB = xg[(size_t)(b * TT + t0) * G4 + colB];

  for (int s = 0; s < TT; ++s) {
    float acc0 = bf2f(xA);
    float acc1 = 0.f;
    float acc2 = bf2f(xB);
    float acc3 = 0.f;
    // prefetch next step's x-gate pair (hide HBM latency under compute)
    if (s + 1 < TT) {
      const int t1 = dir ? (TT - 2 - s) : (s + 1);
      const ushort16* xr1 = xg + (size_t)(b * TT + t1) * G4;
      xA = xr1[colA];
      xB = xr1[colB];
    }
    const uint4* hb = (const uint4*)h2buf[s & 1];
    #pragma unroll
    for (int blk = 0; blk < 32; ++blk) {
      const uint4 hq = hb[blk];                  // wave-uniform b128 broadcast
      #pragma unroll
      for (int j = 0; j < 4; ++j) {
        const int k2 = blk * 4 + j;
        const uint32 hu = (j == 0) ? hq.x : (j == 1) ? hq.y : (j == 2) ? hq.z : hq.w;
        const half2t hh = __builtin_bit_cast(half2t, hu);
        if (k2 < KR) {
          if (j & 1) { acc1 = fdot2_(wA[k2], hh, acc1); acc3 = fdot2_(wB[k2], hh, acc3); }
          else       { acc0 = fdot2_(wA[k2], hh, acc0); acc2 = fdot2_(wB[k2], hh, acc2); }
        } else {
          const uint2 wp = *(const uint2*)(wl + (k2 - KR) * 128);
          if (j & 1) { acc1 = fdot2_(wp.x, hh, acc1); acc3 = fdot2_(wp.y, hh, acc3); }
          else       { acc0 = fdot2_(wp.x, hh, acc0); acc2 = fdot2_(wp.y, hh, acc2); }
        }
      }
    }
    gate[colA] = acc0 + acc1;
    gate[colB] = acc2 + acc3;
    __syncthreads();
    if (tid < 256) {
      const float gi = gate[tid];
      const float gf = gate[256 + tid];
      const float gg = gate[512 + tid];
      const float go = gate[768 + tid];
      c_state = sigf(gf) * c_state + sigf(gi) * tanhf_(gg);
      const float h = sigf(go) * tanhf_(c_state);
      const int row = b * TT + (dir ? (TT - 1 - s) : s);
      enc[(size_t)row * 512 + dir * 256 + tid] = h;
      // pack h -> f16 pairs; even lanes write one dword (conflict-free)
      const int hv = (int)(uint32)__builtin_bit_cast(ushort16, (_Float16)h);
      const int ho = __shfl_xor(hv, 1, 64);
      if (!(tid & 1))
        h2buf[(s + 1) & 1][tid >> 1] = ((uint32)hv & 0xffffu) | ((uint32)ho << 16);
    }
    __syncthreads();
  }
}

// ---------------- K5: logits = enc @ W_dense + b ----------------
__global__ __launch_bounds__(256) void k_dense(const float* __restrict__ enc,
                                               const float* __restrict__ Wd,
                                               const float* __restrict__ bd,
                                               float* __restrict__ logits) {
  __shared__ float Wl[512 * NL];
  __shared__ float bl[NL];
  const int tid = threadIdx.x;
  for (int i = tid; i < 512 * NL; i += 256) Wl[i] = Wd[i];
  if (tid < NL) bl[tid] = bd[tid];
  __syncthreads();
  const int wave = tid >> 6, lane = tid & 63;
  const int row = blockIdx.x * 4 + wave;
  const float* er = enc + (size_t)row * 512;
  float p[NL];
  #pragma unroll
  for (int c = 0; c < NL; ++c) p[c] = 0.f;
  #pragma unroll
  for (int u = 0; u < 8; ++u) {
    const int k = u * 64 + lane;
    const float v = er[k];
    const float* wr = &Wl[k * NL];
    #pragma unroll
    for (int c = 0; c < NL; ++c) p[c] += v * wr[c];
  }
  #pragma unroll
  for (int c = 0; c < NL; ++c) {
    #pragma unroll
    for (int off = 32; off >= 1; off >>= 1) p[c] += __shfl_down(p[c], off, 64);
  }
  if (lane == 0) {
    float* orow = logits + (size_t)row * NL;
    #pragma unroll
    for (int c = 0; c < NL; ++c) orow[c] = p[c] + bl[c];
  }
}

// ---------------- K6: CRF log-likelihood ----------------
__global__ __launch_bounds__(64) void k_crf(const float* __restrict__ logits,
                                            const int* __restrict__ labels,
                                            const int* __restrict__ slen,
                                            const float* __restrict__ trans,
                                            float* __restrict__ out_ll) {
  __shared__ float tr[NL * NL];
  __shared__ float alpha[NL];
  const int b = blockIdx.x;
  const int lane = threadIdx.x;
  for (int i = lane; i < NL * NL; i += 64) tr[i] = trans[i];
  __syncthreads();
  const int len = slen[b];
  const int* tg = labels + b * TT;
  const float* lg = logits + (size_t)b * TT * NL;
  float s = 0.f;
  for (int t = lane; t < TT; t += 64)
    if (t < len) s += lg[t * NL + tg[t]];
  for (int t = lane; t < TT - 1; t += 64)
    if (t + 1 < len) s += tr[tg[t] * NL + tg[t + 1]];
  #pragma unroll
  for (int off = 32; off >= 1; off >>= 1) s += __shfl_down(s, off, 64);
  if (lane < NL) alpha[lane] = lg[lane];
  __syncthreads();
  if (lane < NL) {
    const int j = lane;
    for (int t = 1; t < TT; ++t) {
      if (t < len) {
        float av[NL];
        float m = -1e30f;
        #pragma unroll
        for (int i = 0; i < NL; ++i) { av[i] = alpha[i] + tr[i * NL + j]; m = fmaxf(m, av[i]); }
        float ss = 0.f;
        #pragma unroll
        for (int i = 0; i < NL; ++i) ss += __expf(av[i] - m);
        const float nj = m + __logf(ss) + lg[t * NL + j];
        alpha[j] = nj;
      }
    }
  }
  __syncthreads();
  if (lane == 0) {
    float m = -1e30f;
    #pragma unroll
    for (int i = 0; i < NL; ++i) m = fmaxf(m, alpha[i]);
    float ss = 0.f;
    #pragma unroll
    for (int i = 0; i < NL; ++i) ss += __expf(alpha[i] - m);
    out_ll[b] = s - (m + __logf(ss));
  }
}

extern "C" void kernel_launch(void* const* d_in, const int* in_sizes, int n_in,
                              void* d_out, int out_size, void* d_ws, size_t ws_size,
                              hipStream_t stream) {
  (void)in_sizes; (void)n_in; (void)out_size; (void)ws_size;
  const int*   tokens = (const int*)d_in[0];
  const int*   labels = (const int*)d_in[1];
  const float* emb    = (const float*)d_in[2];
  const float* Wxf    = (const float*)d_in[3];
  const float* Whf    = (const float*)d_in[4];
  const float* bf_    = (const float*)d_in[5];
  const float* Wxb    = (const float*)d_in[6];
  const float* Whb    = (const float*)d_in[7];
  const float* bb_    = (const float*)d_in[8];
  const float* Wd     = (const float*)d_in[9];
  const float* bd     = (const float*)d_in[10];
  const float* trans  = (const float*)d_in[11];
  float* out = (float*)d_out;   // [logits 294912][seq_len 64][ll 64]

  char* ws = (char*)d_ws;
  ushort16* A    = (ushort16*)(ws + 0);           // 16 MB  bf16 emb rows
  ushort16* BT   = (ushort16*)(ws + 16777216);    //  1 MB  Wx^T bf16 (2048x256)
  uint32*   W2f  = (uint32*)  (ws + 17825792);    // 512 KB Wh_f half2 [128][1024]
  uint32*   W2b  = (uint32*)  (ws + 18350080);    // 512 KB
  ushort16* xgf  = (ushort16*)(ws + 18874368);    // 64 MB  bf16 [NT][1024]
  ushort16* xgb  = (ushort16*)(ws + 85983232);    // 64 MB
  float*    enc  = (float*)   (ws + 153092096);   // 64 MB  fp32 [NT][512]
  int*      slen = (int*)     (ws + 220200960);   // 256 B

  k_seqlen<<<BB, 64, 0, stream>>>(tokens, slen, out + NT * NL);
  k_embed <<<NT * 256 / 4 / 256, 256, 0, stream>>>(tokens, emb, A);
  k_wxprep<<<2048 * 256 / 256, 256, 0, stream>>>(Wxf, Wxb, BT);
  k_whprep<<<128 * 1024 / 256, 256, 0, stream>>>(Whf, W2f);
  k_whprep<<<128 * 1024 / 256, 256, 0, stream>>>(Whb, W2b);
  k_gemm_xg<<<dim3(NT / 64, 2048 / 64), 256, 0, stream>>>(A, BT, bf_, bb_, xgf, xgb);
  k_lstm  <<<128, 512, 0, stream>>>(xgf, xgb, W2f, W2b, enc);
  k_dense <<<NT / 4, 256, 0, stream>>>(enc, Wd, bd, out);
  k_crf   <<<BB, 64, 0, stream>>>(out, labels, slen, trans, out + NT * NL + BB);
}